// Round 6
// baseline (28.787 us; speedup 1.0000x reference)
//
#include <hip/hip_runtime.h>

// ReservoirEmbedding: out[tok,:] = sum_r w_eff[reservoir_lookup[base_indices[tok], r], :]
// w_eff row 0 zeroed. base [16,2048] i32, lookup [50257,8] i32, weight [50257,128] f32.
//
// R5: feature-slice XCD pinning. FEATURES=128 split into 8 slices of 16 floats
// (64B). Block b -> slice s = b%8 (round-robin block->XCD dispatch pins slice s
// to XCD s) and token chunk c = b/8 (256 tokens). Each XCD's table working set
// becomes its 64B column-slice: 50257*64B = 3.2MB < 4MB L2 -> gathers turn into
// L2 hits; fabric traffic drops from ~134MB to ~26MB table + 17MB out.
// 1024 blocks = 4/CU, all co-resident (no dispatch drift). Nontemporal output
// stores keep L2 dedicated to the table slice.

#define VOCAB 50257
#define FEATURES 128
#define RESERVOIR 8
#define NTOK (16 * 2048)
#define NSLICE 8
#define SLICE_F 16            // floats per slice (64B)
#define TOK_PER_BLOCK 256
#define PASSES 4              // 256 threads / 4 lanes-per-token = 64 tokens/pass

typedef float float4v __attribute__((ext_vector_type(4)));

__global__ __launch_bounds__(256, 4) void reservoir_embed_kernel(
    const int* __restrict__ base_indices,      // [NTOK]
    const int* __restrict__ reservoir_lookup,  // [VOCAB][RESERVOIR]
    const float* __restrict__ weight,          // [VOCAB][FEATURES]
    float* __restrict__ out)                   // [NTOK][FEATURES]
{
    const int tid   = threadIdx.x;
    const int slice = blockIdx.x & (NSLICE - 1);     // pinned to XCD slice via %8
    const int chunk = blockIdx.x >> 3;               // 0..127
    const int c     = tid & 3;                       // lane within 4-lane token cluster
    const int fbase = slice * SLICE_F + c * 4;       // this lane's 4 features

    const int tok0 = chunk * TOK_PER_BLOCK;

#pragma unroll 2
    for (int p = 0; p < PASSES; ++p) {
        const int tok = tok0 + p * 64 + (tid >> 2);

        const int base = base_indices[tok];          // 4 lanes same addr -> broadcast
        const int4* rlp = reinterpret_cast<const int4*>(
            reservoir_lookup + base * RESERVOIR);
        const int4 i0 = rlp[0];
        const int4 i1 = rlp[1];
        const int idx[RESERVOIR] = {i0.x, i0.y, i0.z, i0.w, i1.x, i1.y, i1.z, i1.w};

        // 8 gathered float4 loads from this XCD's L2-resident column slice.
        float4v rows[RESERVOIR];
#pragma unroll
        for (int r = 0; r < RESERVOIR; ++r) {
            rows[r] = *reinterpret_cast<const float4v*>(
                weight + (((unsigned)idx[r]) << 7) + fbase);
        }

        float4v acc = {0.f, 0.f, 0.f, 0.f};
#pragma unroll
        for (int r = 0; r < RESERVOIR; ++r) {
            const float m = (idx[r] != 0) ? 1.0f : 0.0f;   // frozen row 0
            acc += m * rows[r];
        }

        float4v* op = reinterpret_cast<float4v*>(
            out + (unsigned)tok * FEATURES + fbase);
        __builtin_nontemporal_store(acc, op);
    }
}

extern "C" void kernel_launch(void* const* d_in, const int* in_sizes, int n_in,
                              void* d_out, int out_size, void* d_ws, size_t ws_size,
                              hipStream_t stream) {
    (void)in_sizes; (void)n_in; (void)out_size; (void)d_ws; (void)ws_size;
    const int*   base_indices     = (const int*)d_in[0];
    const int*   reservoir_lookup = (const int*)d_in[1];
    const float* weight           = (const float*)d_in[2];
    float*       out              = (float*)d_out;

    // 8 slices x 128 chunks = 1024 blocks (4/CU, fully co-resident).
    const int blocks  = NSLICE * (NTOK / TOK_PER_BLOCK);
    reservoir_embed_kernel<<<blocks, 256, 0, stream>>>(
        base_indices, reservoir_lookup, weight, out);
}

// Round 7
// 24.043 us; speedup vs baseline: 1.1973x; 1.1973x over previous
//
#include <hip/hip_runtime.h>

// ReservoirEmbedding: out[tok,:] = sum_r w_eff[reservoir_lookup[base_indices[tok], r], :]
// w_eff row 0 zeroed. base [16,2048] i32, lookup [50257,8] i32, weight [50257,128] f32.
//
// R6: per-group SORTED SWEEP. Each 32-lane group owns 4 tokens (32 pairs, one
// per lane). Keys (idx<<3|t) bitonic-sorted in-register, then all 32 gathers
// issued unconditionally in ascending-idx order with a 4-deep pipeline.
// In-flight vocab window = 4/32 of table ~ 3.2MB; all groups sweep
// monotonically from an aligned start (1024 blocks = 4/CU co-resident,
// __syncthreads every 8 pairs bounds drift) -> chip-wide instantaneous working
// set fits per-XCD L2 -> gathers become L2 hits -> less fabric traffic.
// R4 proved phasing raises L2 absorption (FETCH 57.8MB vs 134MB requests);
// this keeps that locality with R0's dense issue + register accumulation.

#define VOCAB 50257
#define FEATURES 128
#define RESERVOIR 8
#define NTOK (16 * 2048)
#define TPG 4        // tokens per 32-lane group
#define NPAIR 32     // TPG * RESERVOIR, one pair per lane
#define DEPTH 4      // load pipeline depth (in-flight vocab window = DEPTH/NPAIR)

typedef float float4v __attribute__((ext_vector_type(4)));

__global__ __launch_bounds__(256, 4) void reservoir_embed_kernel(
    const int* __restrict__ base_indices,      // [NTOK]
    const int* __restrict__ reservoir_lookup,  // [VOCAB][RESERVOIR]
    const float* __restrict__ weight,          // [VOCAB][FEATURES]
    float* __restrict__ out)                   // [NTOK][FEATURES]
{
    const int tid  = threadIdx.x;
    const int gid  = blockIdx.x * 256 + tid;
    const int grp  = gid >> 5;          // 32-lane group
    const int lane = gid & 31;
    const int t0   = grp * TPG;

    // Lane owns pair (t = lane>>3, r = lane&7).
    const int t_own = lane >> 3;
    const int r_own = lane & 7;
    const int base  = base_indices[t0 + t_own];                   // 8 lanes/addr -> broadcast
    const int myidx = reservoir_lookup[base * RESERVOIR + r_own]; // 32B segs, coalesced

    // Sort key: idx in high bits, token-slot in low 3 bits. Any permutation is
    // correct (cswap preserves the multiset); order only affects locality.
    int key = (myidx << 3) | t_own;

    // Bitonic sort of 32 keys across the group (ascending by idx).
#pragma unroll
    for (int m = 2; m <= 32; m <<= 1) {
#pragma unroll
        for (int s = m >> 1; s >= 1; s >>= 1) {
            const int partner = __shfl_xor(key, s, 32);
            const bool asc    = ((lane & m) == 0);   // m=32 -> true for all
            const bool lower  = ((lane & s) == 0);
            const int mn = min(key, partner);
            const int mx = max(key, partner);
            key = (lower == asc) ? mn : mx;
        }
    }

    float4v acc[TPG];
#pragma unroll
    for (int j = 0; j < TPG; ++j) acc[j] = (float4v){0.f, 0.f, 0.f, 0.f};

    // 4-deep software pipeline over the 32 sorted pairs.
    int     kq[DEPTH];
    float4v rq[DEPTH];
#pragma unroll
    for (int k = 0; k < DEPTH; ++k) {
        kq[k] = __shfl(key, k, 32);
        rq[k] = *reinterpret_cast<const float4v*>(
            weight + (((unsigned)kq[k] >> 3) << 7) + (lane << 2));
    }

#pragma unroll
    for (int k = 0; k < NPAIR; ++k) {
        const int     q   = k & (DEPTH - 1);   // static under full unroll
        const int     ck  = kq[q];
        const float4v row = rq[q];
        if (k + DEPTH < NPAIR) {
            const int nk = __shfl(key, k + DEPTH, 32);
            kq[q] = nk;
            rq[q] = *reinterpret_cast<const float4v*>(
                weight + (((unsigned)nk >> 3) << 7) + (lane << 2));
        }
        const float m  = ((ck >> 3) != 0) ? 1.0f : 0.0f;  // frozen row 0
        const int   tt = ck & 7;                          // token slot in [0,TPG)
#pragma unroll
        for (int j = 0; j < TPG; ++j) {
            const float mj = (tt == j) ? m : 0.0f;
            acc[j] += mj * row;
        }
        if ((k & 7) == 7 && k + 1 < NPAIR) __syncthreads();  // bound drift
    }

#pragma unroll
    for (int j = 0; j < TPG; ++j) {
        float4v* op = reinterpret_cast<float4v*>(
            out + (unsigned)(t0 + j) * FEATURES + (lane << 2));
        __builtin_nontemporal_store(acc[j], op);
    }
}

extern "C" void kernel_launch(void* const* d_in, const int* in_sizes, int n_in,
                              void* d_out, int out_size, void* d_ws, size_t ws_size,
                              hipStream_t stream) {
    (void)in_sizes; (void)n_in; (void)out_size; (void)d_ws; (void)ws_size;
    const int*   base_indices     = (const int*)d_in[0];
    const int*   reservoir_lookup = (const int*)d_in[1];
    const float* weight           = (const float*)d_in[2];
    float*       out              = (float*)d_out;

    const int threads = 256;                    // 8 groups per block
    const int groups  = NTOK / TPG;             // 8192 groups
    const int blocks  = groups * 32 / threads;  // 1024 blocks = 4/CU co-resident
    reservoir_embed_kernel<<<blocks, threads, 0, stream>>>(
        base_indices, reservoir_lookup, weight, out);
}